// Round 1
// baseline (825.641 us; speedup 1.0000x reference)
//
#include <hip/hip_runtime.h>
#include <math.h>

#define NQ 40000
#define DIM 256
#define NH 8
#define NP 6
#define HD 32
#define GH 200
#define GW 200

typedef short bf16x8 __attribute__((ext_vector_type(8)));
typedef float f32x4 __attribute__((ext_vector_type(4)));

__device__ __forceinline__ unsigned short f2bf(float f) {
    unsigned int u = __builtin_bit_cast(unsigned int, f);
    u += 0x7fffu + ((u >> 16) & 1u);
    return (unsigned short)(u >> 16);
}
__device__ __forceinline__ float bf2f(unsigned short h) {
    return __builtin_bit_cast(float, ((unsigned int)h) << 16);
}

// ---------------------------------------------------------------------------
// GEMM: C[M,N] = epilogue(A[M,K=256] * B[256,N] + bias[N])
// EPI: 0 = none (float out), 1 = exact gelu (float out), 2 = bf16 out
// block: 256 threads = 4 waves (2x2), block tile 64x64, wave tile 32x32,
// K-step 32 via mfma_f32_16x16x32_bf16. M must be a multiple of 64 (40000 ok).
// ---------------------------------------------------------------------------
template <int EPI>
__global__ void __launch_bounds__(256)
gemm_kernel(const float* __restrict__ A, const float* __restrict__ B,
            const float* __restrict__ bias, void* __restrict__ C, int M, int N) {
    const int K = 256;
    __shared__ __align__(16) unsigned short As[64][48];   // row-major [m][k], padded
    __shared__ __align__(16) unsigned short Bs[64][48];   // transposed [n][k], padded

    const int tid = threadIdx.x;
    const int lane = tid & 63;
    const int wave = tid >> 6;
    const int quad = lane >> 4;
    const int l16 = lane & 15;
    const int wm = wave >> 1;   // 0..1
    const int wn = wave & 1;    // 0..1
    const int bm0 = blockIdx.y * 64;
    const int bn0 = blockIdx.x * 64;

    f32x4 acc[2][2];
#pragma unroll
    for (int i = 0; i < 2; ++i)
#pragma unroll
        for (int j = 0; j < 2; ++j)
#pragma unroll
            for (int r = 0; r < 4; ++r) acc[i][j][r] = 0.0f;

    // staging indices
    const int ar = tid >> 2;           // 0..63   (A row)
    const int ac = (tid & 3) * 4;      // 0,4,8,12
    const int bk = tid >> 3;           // 0..31   (B k-row)
    const int bn = (tid & 7) * 8;      // 0..56   (B n-col group)

    for (int kt = 0; kt < 8; ++kt) {
        const int k0 = kt * 32;
        __syncthreads();
        // stage A (64 x 32 fp32 -> bf16)
        {
            const float* ap = A + (size_t)(bm0 + ar) * K + k0;
#pragma unroll
            for (int p = 0; p < 2; ++p) {
                float4 v4 = *(const float4*)(ap + ac + p * 16);
                const int c = ac + p * 16;
                As[ar][c + 0] = f2bf(v4.x);
                As[ar][c + 1] = f2bf(v4.y);
                As[ar][c + 2] = f2bf(v4.z);
                As[ar][c + 3] = f2bf(v4.w);
            }
        }
        // stage B transposed (32 x 64 fp32 -> bf16 [n][k])
        {
            const float* bp = B + (size_t)(k0 + bk) * N + bn0 + bn;
#pragma unroll
            for (int j = 0; j < 8; ++j) {
                const int n = bn0 + bn + j;
                float v = (n < N) ? bp[j] : 0.0f;
                Bs[bn + j][bk] = f2bf(v);
            }
        }
        __syncthreads();

        bf16x8 af[2], bfr[2];
#pragma unroll
        for (int t = 0; t < 2; ++t) {
            af[t]  = *(const bf16x8*)&As[wm * 32 + t * 16 + l16][quad * 8];
            bfr[t] = *(const bf16x8*)&Bs[wn * 32 + t * 16 + l16][quad * 8];
        }
#pragma unroll
        for (int tm = 0; tm < 2; ++tm)
#pragma unroll
            for (int tn = 0; tn < 2; ++tn)
                acc[tm][tn] = __builtin_amdgcn_mfma_f32_16x16x32_bf16(
                    af[tm], bfr[tn], acc[tm][tn], 0, 0, 0);
    }

    // epilogue + store. C/D layout: col = lane&15, row = quad*4 + reg
#pragma unroll
    for (int tm = 0; tm < 2; ++tm) {
        const int row = bm0 + wm * 32 + tm * 16 + quad * 4;
#pragma unroll
        for (int tn = 0; tn < 2; ++tn) {
            const int col = bn0 + wn * 32 + tn * 16 + l16;
            if (col < N) {
                const float bv = bias[col];
#pragma unroll
                for (int r = 0; r < 4; ++r) {
                    float x = acc[tm][tn][r] + bv;
                    if (EPI == 1) x = 0.5f * x * (1.0f + erff(x * 0.70710678118654752f));
                    if (EPI == 2)
                        ((unsigned short*)C)[(size_t)(row + r) * N + col] = f2bf(x);
                    else
                        ((float*)C)[(size_t)(row + r) * N + col] = x;
                }
            }
        }
    }
}

// ---------------------------------------------------------------------------
// Deformable sampling: one block per query, 8 heads x 32 dims.
// v: (H*W, 256) bf16 with channel = h*32+d. out: (NQ, 256) fp32.
// ---------------------------------------------------------------------------
__global__ void __launch_bounds__(256)
msda_sample(const unsigned short* __restrict__ v, const float* __restrict__ off,
            const float* __restrict__ attn, const float* __restrict__ rp,
            float* __restrict__ out) {
    const int q = blockIdx.x;
    const int h = threadIdx.x >> 5;
    const int d = threadIdx.x & 31;

    const float rx = rp[q * 2 + 0] * (float)GW;
    const float ry = rp[q * 2 + 1] * (float)GH;

    // softmax over 6 points (redundant across the 32 lanes of this head group)
    float lg[NP];
    const float* ap = attn + (size_t)q * (NH * NP) + h * NP;
    float mx = -1e30f;
#pragma unroll
    for (int p = 0; p < NP; ++p) { lg[p] = ap[p]; mx = fmaxf(mx, lg[p]); }
    float s = 0.0f;
#pragma unroll
    for (int p = 0; p < NP; ++p) { lg[p] = expf(lg[p] - mx); s += lg[p]; }
    const float inv = 1.0f / s;

    const float* op = off + (size_t)q * (NH * NP * 2) + h * (NP * 2);
    float acc = 0.0f;
#pragma unroll
    for (int p = 0; p < NP; ++p) {
        const float aw = lg[p] * inv;
        const float lx = rx + op[p * 2 + 0] - 0.5f;
        const float ly = ry + op[p * 2 + 1] - 0.5f;
        const float fx0 = floorf(lx), fy0 = floorf(ly);
        const int x0 = (int)fx0, y0 = (int)fy0;
        const float fx = lx - fx0, fy = ly - fy0;
        const float wx[2] = {1.0f - fx, fx};
        const float wy[2] = {1.0f - fy, fy};
#pragma unroll
        for (int dy = 0; dy < 2; ++dy) {
            const int yi = y0 + dy;
            if (yi < 0 || yi >= GH) continue;
#pragma unroll
            for (int dx = 0; dx < 2; ++dx) {
                const int xi = x0 + dx;
                if (xi < 0 || xi >= GW) continue;
                const float w = aw * wx[dx] * wy[dy];
                const unsigned short g = v[(size_t)(yi * GW + xi) * DIM + h * HD + d];
                acc += bf2f(g) * w;
            }
        }
    }
    out[(size_t)q * DIM + h * HD + d] = acc;
}

// ---------------------------------------------------------------------------
// Fused residual + LayerNorm over D=256. One wave per row, 4 rows per block.
// out = (x+res - mean)/sqrt(var+1e-5)*g + b     (population variance)
// ---------------------------------------------------------------------------
__global__ void __launch_bounds__(256)
ln_res(const float* __restrict__ x, const float* __restrict__ res,
       const float* __restrict__ g, const float* __restrict__ b,
       float* __restrict__ out, int M) {
    const int wave = threadIdx.x >> 6;
    const int lane = threadIdx.x & 63;
    const int row = blockIdx.x * 4 + wave;
    if (row >= M) return;

    const size_t base = (size_t)row * DIM + lane * 4;
    const float4 xv = *(const float4*)(x + base);
    const float4 rv = *(const float4*)(res + base);
    float e[4] = {xv.x + rv.x, xv.y + rv.y, xv.z + rv.z, xv.w + rv.w};

    float s = e[0] + e[1] + e[2] + e[3];
    float sq = e[0] * e[0] + e[1] * e[1] + e[2] * e[2] + e[3] * e[3];
#pragma unroll
    for (int o = 1; o < 64; o <<= 1) {
        s += __shfl_xor(s, o);
        sq += __shfl_xor(sq, o);
    }
    const float mean = s * (1.0f / DIM);
    const float var = sq * (1.0f / DIM) - mean * mean;
    const float rstd = rsqrtf(var + 1e-5f);

    const float4 gv = *(const float4*)(g + lane * 4);
    const float4 bv = *(const float4*)(b + lane * 4);
    float4 o4;
    o4.x = (e[0] - mean) * rstd * gv.x + bv.x;
    o4.y = (e[1] - mean) * rstd * gv.y + bv.y;
    o4.z = (e[2] - mean) * rstd * gv.z + bv.z;
    o4.w = (e[3] - mean) * rstd * gv.w + bv.w;
    *(float4*)(out + base) = o4;
}

extern "C" void kernel_launch(void* const* d_in, const int* in_sizes, int n_in,
                              void* d_out, int out_size, void* d_ws, size_t ws_size,
                              hipStream_t stream) {
    const float* query  = (const float*)d_in[0];
    const float* value  = (const float*)d_in[1];
    const float* rp     = (const float*)d_in[2];
    // d_in[3]=spatial_shapes(int), d_in[4]=level_start_index(int): constants 200,200,0
    const float* W_off  = (const float*)d_in[5];
    const float* b_off  = (const float*)d_in[6];
    const float* W_attn = (const float*)d_in[7];
    const float* b_attn = (const float*)d_in[8];
    const float* W_val  = (const float*)d_in[9];
    const float* b_val  = (const float*)d_in[10];
    const float* W_out  = (const float*)d_in[11];
    const float* b_out  = (const float*)d_in[12];
    const float* ln1_g  = (const float*)d_in[13];
    const float* ln1_b  = (const float*)d_in[14];
    const float* W1     = (const float*)d_in[15];
    const float* b1     = (const float*)d_in[16];
    const float* W2     = (const float*)d_in[17];
    const float* b2     = (const float*)d_in[18];
    const float* ln2_g  = (const float*)d_in[19];
    const float* ln2_b  = (const float*)d_in[20];

    char* ws = (char*)d_ws;
    // layout (bytes):
    //  [0,          20480000)  v_bf16  (40000*256*2)     -- dead after sampling
    //  [20480000,   35840000)  off     (40000*96*4)      -- dead after sampling
    //  [35840000,   43520000)  attn    (40000*48*4)      -- dead after sampling
    //  [43520000,   84480000)  msda    (40000*256*4)     -- dead after W_out gemm
    //  y  reuses [43520000, 84480000)
    //  h1 reuses [0, 40960000)
    //  d_out doubles as scratch for pre-LN gemm outputs
    unsigned short* v_bf = (unsigned short*)(ws);
    float* off  = (float*)(ws + 20480000);
    float* attn = (float*)(ws + 35840000);
    float* msda = (float*)(ws + 43520000);
    float* y    = (float*)(ws + 43520000);
    float* h1   = (float*)(ws + 0);
    float* outp = (float*)d_out;

    dim3 blk(256);
    // v = value @ W_val + b_val  -> bf16
    gemm_kernel<2><<<dim3(4, 625), blk, 0, stream>>>(value, W_val, b_val, (void*)v_bf, NQ, 256);
    // off = query @ W_off + b_off
    gemm_kernel<0><<<dim3(2, 625), blk, 0, stream>>>(query, W_off, b_off, (void*)off, NQ, 96);
    // attn logits = query @ W_attn + b_attn
    gemm_kernel<0><<<dim3(1, 625), blk, 0, stream>>>(query, W_attn, b_attn, (void*)attn, NQ, 48);
    // deformable sampling -> msda (NQ, 256)
    msda_sample<<<dim3(NQ), blk, 0, stream>>>(v_bf, off, attn, rp, msda);
    // y_msda_pre = msda @ W_out + b_out   (into d_out as scratch)
    gemm_kernel<0><<<dim3(4, 625), blk, 0, stream>>>(msda, W_out, b_out, (void*)outp, NQ, 256);
    // y = LN(y_msda_pre + query)
    ln_res<<<dim3(NQ / 4), blk, 0, stream>>>(outp, query, ln1_g, ln1_b, y, NQ);
    // h1 = gelu(y @ W1 + b1)
    gemm_kernel<1><<<dim3(4, 625), blk, 0, stream>>>(y, W1, b1, (void*)h1, NQ, 256);
    // y2p = h1 @ W2 + b2   (into d_out as scratch)
    gemm_kernel<0><<<dim3(4, 625), blk, 0, stream>>>(h1, W2, b2, (void*)outp, NQ, 256);
    // out = LN(y2p + y)   (in-place on d_out; per-row read-then-write)
    ln_res<<<dim3(NQ / 4), blk, 0, stream>>>(outp, y, ln2_g, ln2_b, outp, NQ);
}

// Round 2
// 368.436 us; speedup vs baseline: 2.2409x; 2.2409x over previous
//
#include <hip/hip_runtime.h>
#include <math.h>

#define NQ 40000
#define DIM 256
#define NH 8
#define NP 6
#define HD 32
#define GH 200
#define GW 200

typedef short bf16x8 __attribute__((ext_vector_type(8)));
typedef float f32x4 __attribute__((ext_vector_type(4)));

__device__ __forceinline__ unsigned short f2bf(float f) {
    unsigned int u = __builtin_bit_cast(unsigned int, f);
    u += 0x7fffu + ((u >> 16) & 1u);
    return (unsigned short)(u >> 16);
}
__device__ __forceinline__ float bf2f(unsigned short h) {
    return __builtin_bit_cast(float, ((unsigned int)h) << 16);
}

// ---------------------------------------------------------------------------
// fp32 -> bf16 elementwise, 8 elems/thread
// ---------------------------------------------------------------------------
__global__ void __launch_bounds__(256)
f2b_kernel(const float* __restrict__ src, unsigned short* __restrict__ dst, int n8) {
    const int i = blockIdx.x * 256 + threadIdx.x;
    if (i >= n8) return;
    const float4* s = (const float4*)src;
    float4 a = s[(size_t)i * 2], b = s[(size_t)i * 2 + 1];
    bf16x8 o;
    o[0] = (short)f2bf(a.x); o[1] = (short)f2bf(a.y);
    o[2] = (short)f2bf(a.z); o[3] = (short)f2bf(a.w);
    o[4] = (short)f2bf(b.x); o[5] = (short)f2bf(b.y);
    o[6] = (short)f2bf(b.z); o[7] = (short)f2bf(b.w);
    *(bf16x8*)(dst + (size_t)i * 8) = o;
}

// ---------------------------------------------------------------------------
// Weight prep: transpose K x N fp32 -> [N][K] bf16 rows packed into Bt.
// Bt row offsets: Wval 0, Woff 256, Wattn 352, Wout 400, W1 656, W2 912.
// Also packs bias_oa[144] = concat(b_off, b_attn).
// grid dim3(4,4,6), block 256.
// ---------------------------------------------------------------------------
__global__ void __launch_bounds__(256)
wtrans_kernel(const float* __restrict__ Wval, const float* __restrict__ Woff,
              const float* __restrict__ Wattn, const float* __restrict__ Wout,
              const float* __restrict__ W1, const float* __restrict__ W2,
              const float* __restrict__ b_off, const float* __restrict__ b_attn,
              unsigned short* __restrict__ Bt, float* __restrict__ bias_oa) {
    __shared__ float T[64][65];
    const int m = blockIdx.z;
    const float* src; int N; int dr0;
    if (m == 0)      { src = Wval;  N = 256; dr0 = 0; }
    else if (m == 1) { src = Woff;  N = 96;  dr0 = 256; }
    else if (m == 2) { src = Wattn; N = 48;  dr0 = 352; }
    else if (m == 3) { src = Wout;  N = 256; dr0 = 400; }
    else if (m == 4) { src = W1;    N = 256; dr0 = 656; }
    else             { src = W2;    N = 256; dr0 = 912; }

    if (m == 1 && blockIdx.x == 0 && blockIdx.y == 0 && threadIdx.x < 144)
        bias_oa[threadIdx.x] = threadIdx.x < 96 ? b_off[threadIdx.x]
                                                : b_attn[threadIdx.x - 96];

    const int n0 = blockIdx.x * 64, k0 = blockIdx.y * 64;
    if (n0 >= N) return;
    const int col = threadIdx.x & 63, rg = threadIdx.x >> 6;
#pragma unroll
    for (int i = 0; i < 16; ++i) {
        const int r = rg + 4 * i;  // k-local
        T[r][col] = (n0 + col < N) ? src[(size_t)(k0 + r) * N + n0 + col] : 0.0f;
    }
    __syncthreads();
#pragma unroll
    for (int i = 0; i < 16; ++i) {
        const int nl = rg + 4 * i;
        if (n0 + nl < N)
            Bt[(size_t)(dr0 + n0 + nl) * 256 + k0 + col] = f2bf(T[col][nl]);
    }
}

// ---------------------------------------------------------------------------
// m97-style GEMM: C[M,N] = epi(A[M,256] @ Bt[N,256]^T + bias)
// A, Bt bf16. 128x128 block tile, 4 waves each 64x64, BK=32,
// global_load_lds width-16 staging, 16 MFMA / wave / K-step.
// EPI: 0 = fp32 out, 1 = exact-gelu -> bf16 out, 2 = bf16 out.
// ---------------------------------------------------------------------------
template <int EPI>
__global__ void __launch_bounds__(256)
gemm_bt(const unsigned short* __restrict__ A, const unsigned short* __restrict__ Bt,
        const float* __restrict__ bias, void* __restrict__ C,
        int M, int N, int ldc) {
    __shared__ __align__(16) unsigned short As[128 * 32];
    __shared__ __align__(16) unsigned short Bs[128 * 32];

    const int tid = threadIdx.x, lane = tid & 63, wave = tid >> 6;
    const int quad = lane >> 4, l16 = lane & 15;
    const int wm = wave >> 1, wn = wave & 1;
    const int bm0 = blockIdx.y * 128, bn0 = blockIdx.x * 128;

    f32x4 acc[4][4] = {};

    const int rl = lane >> 2;         // 0..15 row within 16-row group
    const int c8 = (lane & 3) * 8;    // element col within 32

    for (int kt = 0; kt < 8; ++kt) {
        const int k0 = kt * 32;
        __syncthreads();
#pragma unroll
        for (int i = 0; i < 2; ++i) {
            const int rgrp = i * 64 + wave * 16;         // wave-uniform row group
            const int gA = min(bm0 + rgrp + rl, M - 1);
            const unsigned short* gpa = A + (size_t)gA * 256 + k0 + c8;
            __builtin_amdgcn_global_load_lds(
                (const __attribute__((address_space(1))) void*)gpa,
                (__attribute__((address_space(3))) void*)(As + (size_t)rgrp * 32),
                16, 0, 0);
            const int gB = min(bn0 + rgrp + rl, N - 1);
            const unsigned short* gpb = Bt + (size_t)gB * 256 + k0 + c8;
            __builtin_amdgcn_global_load_lds(
                (const __attribute__((address_space(1))) void*)gpb,
                (__attribute__((address_space(3))) void*)(Bs + (size_t)rgrp * 32),
                16, 0, 0);
        }
        __syncthreads();

        bf16x8 af[4], bw[4];
#pragma unroll
        for (int t = 0; t < 4; ++t) {
            af[t] = *(const bf16x8*)&As[(wm * 64 + t * 16 + l16) * 32 + quad * 8];
            bw[t] = *(const bf16x8*)&Bs[(wn * 64 + t * 16 + l16) * 32 + quad * 8];
        }
#pragma unroll
        for (int tm = 0; tm < 4; ++tm)
#pragma unroll
            for (int tn = 0; tn < 4; ++tn)
                acc[tm][tn] = __builtin_amdgcn_mfma_f32_16x16x32_bf16(
                    af[tm], bw[tn], acc[tm][tn], 0, 0, 0);
    }

    // C/D layout: col = lane&15, row = quad*4 + reg
#pragma unroll
    for (int tm = 0; tm < 4; ++tm) {
        const int row0 = bm0 + wm * 64 + tm * 16 + quad * 4;
#pragma unroll
        for (int tn = 0; tn < 4; ++tn) {
            const int col = bn0 + wn * 64 + tn * 16 + l16;
            if (col < N) {
                const float bv = bias[col];
#pragma unroll
                for (int r = 0; r < 4; ++r) {
                    const int row = row0 + r;
                    if (row < M) {
                        float x = acc[tm][tn][r] + bv;
                        if (EPI == 1) {
                            x = 0.5f * x * (1.0f + erff(x * 0.70710678118654752f));
                            ((unsigned short*)C)[(size_t)row * ldc + col] = f2bf(x);
                        } else if (EPI == 2) {
                            ((unsigned short*)C)[(size_t)row * ldc + col] = f2bf(x);
                        } else {
                            ((float*)C)[(size_t)row * ldc + col] = x;
                        }
                    }
                }
            }
        }
    }
}

// ---------------------------------------------------------------------------
// Deformable sampling, vectorized: thread = (query, head, 8-channel slice).
// Block 256 = 8 queries x 8 heads x 4 slices. 16B gathers.
// oa: bf16 [NQ][144] = {offsets[96] | logits[48]}. out: bf16 [NQ][256].
// ---------------------------------------------------------------------------
__global__ void __launch_bounds__(256)
msda_sample(const unsigned short* __restrict__ v,
            const unsigned short* __restrict__ oa,
            const float* __restrict__ rp,
            unsigned short* __restrict__ out) {
    const int tid = threadIdx.x;
    const int slot = tid >> 2;            // 0..63
    const int q = blockIdx.x * 8 + (slot >> 3);
    const int h = slot & 7;
    const int c0 = (tid & 3) * 8;

    const float rx = rp[q * 2 + 0] * (float)GW;
    const float ry = rp[q * 2 + 1] * (float)GH;

    const unsigned short* oaq = oa + (size_t)q * 144;
    float lg[NP];
    float mx = -1e30f;
#pragma unroll
    for (int p = 0; p < NP; ++p) {
        lg[p] = bf2f(oaq[96 + h * NP + p]);
        mx = fmaxf(mx, lg[p]);
    }
    float s = 0.0f;
#pragma unroll
    for (int p = 0; p < NP; ++p) { lg[p] = expf(lg[p] - mx); s += lg[p]; }
    const float inv = 1.0f / s;

    float acc[8] = {};
#pragma unroll
    for (int p = 0; p < NP; ++p) {
        const float aw = lg[p] * inv;
        const float lx = rx + bf2f(oaq[h * 12 + p * 2 + 0]) - 0.5f;
        const float ly = ry + bf2f(oaq[h * 12 + p * 2 + 1]) - 0.5f;
        const float fx0 = floorf(lx), fy0 = floorf(ly);
        const int x0 = (int)fx0, y0 = (int)fy0;
        const float fx = lx - fx0, fy = ly - fy0;
#pragma unroll
        for (int dy = 0; dy < 2; ++dy) {
            const int yi = y0 + dy;
            const float wyv = dy ? fy : 1.0f - fy;
#pragma unroll
            for (int dx = 0; dx < 2; ++dx) {
                const int xi = x0 + dx;
                const float wxv = dx ? fx : 1.0f - fx;
                const bool valid = (xi >= 0) & (xi < GW) & (yi >= 0) & (yi < GH);
                const int yc = min(max(yi, 0), GH - 1);
                const int xc = min(max(xi, 0), GW - 1);
                const float w = valid ? aw * wxv * wyv : 0.0f;
                const bf16x8 g = *(const bf16x8*)&v[((size_t)(yc * GW + xc)) * 256 + h * 32 + c0];
#pragma unroll
                for (int j = 0; j < 8; ++j)
                    acc[j] += bf2f((unsigned short)g[j]) * w;
            }
        }
    }
    bf16x8 o;
#pragma unroll
    for (int j = 0; j < 8; ++j) o[j] = (short)f2bf(acc[j]);
    *(bf16x8*)&out[(size_t)q * 256 + h * 32 + c0] = o;
}

// ---------------------------------------------------------------------------
// Fused residual + LayerNorm over D=256 (+ optional bf16 copy of output).
// One wave per row, 4 rows per block.
// ---------------------------------------------------------------------------
__global__ void __launch_bounds__(256)
ln_res(const float* __restrict__ x, const float* __restrict__ res,
       const float* __restrict__ g, const float* __restrict__ b,
       float* __restrict__ out, unsigned short* __restrict__ out_bf, int M) {
    const int wave = threadIdx.x >> 6;
    const int lane = threadIdx.x & 63;
    const int row = blockIdx.x * 4 + wave;
    if (row >= M) return;

    const size_t base = (size_t)row * DIM + lane * 4;
    const float4 xv = *(const float4*)(x + base);
    const float4 rv = *(const float4*)(res + base);
    float e[4] = {xv.x + rv.x, xv.y + rv.y, xv.z + rv.z, xv.w + rv.w};

    float s = e[0] + e[1] + e[2] + e[3];
    float sq = e[0] * e[0] + e[1] * e[1] + e[2] * e[2] + e[3] * e[3];
#pragma unroll
    for (int o = 1; o < 64; o <<= 1) {
        s += __shfl_xor(s, o);
        sq += __shfl_xor(sq, o);
    }
    const float mean = s * (1.0f / DIM);
    const float var = sq * (1.0f / DIM) - mean * mean;
    const float rstd = rsqrtf(var + 1e-5f);

    const float4 gv = *(const float4*)(g + lane * 4);
    const float4 bv = *(const float4*)(b + lane * 4);
    float4 o4;
    o4.x = (e[0] - mean) * rstd * gv.x + bv.x;
    o4.y = (e[1] - mean) * rstd * gv.y + bv.y;
    o4.z = (e[2] - mean) * rstd * gv.z + bv.z;
    o4.w = (e[3] - mean) * rstd * gv.w + bv.w;
    *(float4*)(out + base) = o4;
    if (out_bf) {
        bf16x8 ob;
        ob[0] = (short)f2bf(o4.x); ob[1] = (short)f2bf(o4.y);
        ob[2] = (short)f2bf(o4.z); ob[3] = (short)f2bf(o4.w);
        // store only 4 (8B) — pack as two dwords
        *(uint2*)(out_bf + base) = *(uint2*)&ob;
    }
}

extern "C" void kernel_launch(void* const* d_in, const int* in_sizes, int n_in,
                              void* d_out, int out_size, void* d_ws, size_t ws_size,
                              hipStream_t stream) {
    const float* query  = (const float*)d_in[0];
    const float* value  = (const float*)d_in[1];
    const float* rp     = (const float*)d_in[2];
    const float* W_off  = (const float*)d_in[5];
    const float* b_off  = (const float*)d_in[6];
    const float* W_attn = (const float*)d_in[7];
    const float* b_attn = (const float*)d_in[8];
    const float* W_val  = (const float*)d_in[9];
    const float* b_val  = (const float*)d_in[10];
    const float* W_out  = (const float*)d_in[11];
    const float* b_out  = (const float*)d_in[12];
    const float* ln1_g  = (const float*)d_in[13];
    const float* ln1_b  = (const float*)d_in[14];
    const float* W1     = (const float*)d_in[15];
    const float* b1     = (const float*)d_in[16];
    const float* W2     = (const float*)d_in[17];
    const float* b2     = (const float*)d_in[18];
    const float* ln2_g  = (const float*)d_in[19];
    const float* ln2_b  = (const float*)d_in[20];

    char* ws = (char*)d_ws;
    // layout (bytes), total footprint 82,575,360 <= proven 84,480,000:
    //  [0,        598016)  Bt weights (1168 rows x 256 bf16)
    //  [598016,   598592)  bias_oa (144 f32)
    //  [655360, 21135360)  query_bf  -> h1_bf      (after G2)
    //  [21135360,41615360) value_bf  -> msda_bf    (after G1) -> y_bf (after G3)
    //  [41615360,62095360) v_bf      (dead after sampling)
    //  [62095360,73615360) oa_bf     (dead after sampling)
    //  [41615360,82575360) y fp32    (written at LN1, overlaps dead v_bf/oa_bf)
    unsigned short* Bt       = (unsigned short*)ws;
    float*          bias_oa  = (float*)(ws + 598016);
    unsigned short* query_bf = (unsigned short*)(ws + 655360);
    unsigned short* h1_bf    = query_bf;
    unsigned short* value_bf = (unsigned short*)(ws + 21135360);
    unsigned short* msda_bf  = value_bf;
    unsigned short* y_bf     = value_bf;
    unsigned short* v_bf     = (unsigned short*)(ws + 41615360);
    unsigned short* oa_bf    = (unsigned short*)(ws + 62095360);
    float*          y        = (float*)(ws + 41615360);
    float*          outp     = (float*)d_out;

    dim3 blk(256);
    f2b_kernel<<<dim3(5000), blk, 0, stream>>>(query, query_bf, 1280000);
    f2b_kernel<<<dim3(5000), blk, 0, stream>>>(value, value_bf, 1280000);
    wtrans_kernel<<<dim3(4, 4, 6), blk, 0, stream>>>(W_val, W_off, W_attn, W_out, W1, W2,
                                                     b_off, b_attn, Bt, bias_oa);
    // v = value @ W_val + b_val -> bf16
    gemm_bt<2><<<dim3(2, 313), blk, 0, stream>>>(value_bf, Bt, b_val, (void*)v_bf, NQ, 256, 256);
    // offattn = query @ [W_off|W_attn] + bias -> bf16 [NQ][144]
    gemm_bt<2><<<dim3(2, 313), blk, 0, stream>>>(query_bf, Bt + 256 * 256, bias_oa,
                                                 (void*)oa_bf, NQ, 144, 144);
    // sampling -> msda bf16
    msda_sample<<<dim3(5000), blk, 0, stream>>>(v_bf, oa_bf, rp, msda_bf);
    // y_msda_pre = msda @ W_out + b_out (fp32, into d_out as scratch)
    gemm_bt<0><<<dim3(2, 313), blk, 0, stream>>>(msda_bf, Bt + 400 * 256, b_out,
                                                 (void*)outp, NQ, 256, 256);
    // y = LN(y_msda_pre + query), also bf16 copy
    ln_res<<<dim3(10000), blk, 0, stream>>>(outp, query, ln1_g, ln1_b, y, y_bf, NQ);
    // h1 = gelu(y @ W1 + b1) -> bf16
    gemm_bt<1><<<dim3(2, 313), blk, 0, stream>>>(y_bf, Bt + 656 * 256, b1,
                                                 (void*)h1_bf, NQ, 256, 256);
    // y2p = h1 @ W2 + b2 (fp32, into d_out)
    gemm_bt<0><<<dim3(2, 313), blk, 0, stream>>>(h1_bf, Bt + 912 * 256, b2,
                                                 (void*)outp, NQ, 256, 256);
    // out = LN(y2p + y), in place
    ln_res<<<dim3(10000), blk, 0, stream>>>(outp, y, ln2_g, ln2_b, outp, nullptr, NQ);
}

// Round 3
// 357.423 us; speedup vs baseline: 2.3100x; 1.0308x over previous
//
#include <hip/hip_runtime.h>
#include <math.h>

#define NQ 40000
#define DIM 256
#define NH 8
#define NP 6
#define HD 32
#define GH 200
#define GW 200
#define TS 8          // sort tile size (cells)
#define TNX 25        // tiles per axis
#define NT 625        // total tiles

typedef short bf16x8 __attribute__((ext_vector_type(8)));
typedef float f32x4 __attribute__((ext_vector_type(4)));

__device__ __forceinline__ unsigned short f2bf(float f) {
    unsigned int u = __builtin_bit_cast(unsigned int, f);
    u += 0x7fffu + ((u >> 16) & 1u);
    return (unsigned short)(u >> 16);
}
__device__ __forceinline__ float bf2f(unsigned short h) {
    return __builtin_bit_cast(float, ((unsigned int)h) << 16);
}

// ---------------------------------------------------------------------------
// fp32 -> bf16 elementwise for query (blocks 0..4999) and value (5000..9999)
// ---------------------------------------------------------------------------
__global__ void __launch_bounds__(256)
f2b_kernel(const float* __restrict__ q, unsigned short* __restrict__ qd,
           const float* __restrict__ v, unsigned short* __restrict__ vd) {
    int b = blockIdx.x;
    const float* src; unsigned short* dst;
    if (b < 5000) { src = q; dst = qd; } else { src = v; dst = vd; b -= 5000; }
    const int i = b * 256 + threadIdx.x;   // < 1,280,000 always
    const float4* s = (const float4*)src;
    float4 a = s[(size_t)i * 2], c = s[(size_t)i * 2 + 1];
    bf16x8 o;
    o[0] = (short)f2bf(a.x); o[1] = (short)f2bf(a.y);
    o[2] = (short)f2bf(a.z); o[3] = (short)f2bf(a.w);
    o[4] = (short)f2bf(c.x); o[5] = (short)f2bf(c.y);
    o[6] = (short)f2bf(c.z); o[7] = (short)f2bf(c.w);
    *(bf16x8*)(dst + (size_t)i * 8) = o;
}

// ---------------------------------------------------------------------------
// Weight prep (transpose to [N][K] bf16) — unchanged from R2.
// ---------------------------------------------------------------------------
__global__ void __launch_bounds__(256)
wtrans_kernel(const float* __restrict__ Wval, const float* __restrict__ Woff,
              const float* __restrict__ Wattn, const float* __restrict__ Wout,
              const float* __restrict__ W1, const float* __restrict__ W2,
              const float* __restrict__ b_off, const float* __restrict__ b_attn,
              unsigned short* __restrict__ Bt, float* __restrict__ bias_oa) {
    __shared__ float T[64][65];
    const int m = blockIdx.z;
    const float* src; int N; int dr0;
    if (m == 0)      { src = Wval;  N = 256; dr0 = 0; }
    else if (m == 1) { src = Woff;  N = 96;  dr0 = 256; }
    else if (m == 2) { src = Wattn; N = 48;  dr0 = 352; }
    else if (m == 3) { src = Wout;  N = 256; dr0 = 400; }
    else if (m == 4) { src = W1;    N = 256; dr0 = 656; }
    else             { src = W2;    N = 256; dr0 = 912; }

    if (m == 1 && blockIdx.x == 0 && blockIdx.y == 0 && threadIdx.x < 144)
        bias_oa[threadIdx.x] = threadIdx.x < 96 ? b_off[threadIdx.x]
                                                : b_attn[threadIdx.x - 96];

    const int n0 = blockIdx.x * 64, k0 = blockIdx.y * 64;
    if (n0 >= N) return;
    const int col = threadIdx.x & 63, rg = threadIdx.x >> 6;
#pragma unroll
    for (int i = 0; i < 16; ++i) {
        const int r = rg + 4 * i;
        T[r][col] = (n0 + col < N) ? src[(size_t)(k0 + r) * N + n0 + col] : 0.0f;
    }
    __syncthreads();
#pragma unroll
    for (int i = 0; i < 16; ++i) {
        const int nl = rg + 4 * i;
        if (n0 + nl < N)
            Bt[(size_t)(dr0 + n0 + nl) * 256 + k0 + col] = f2bf(T[col][nl]);
    }
}

// ---------------------------------------------------------------------------
// Query spatial sort: counting sort by 8x8-cell tile of the reference point.
// ---------------------------------------------------------------------------
__device__ __forceinline__ int tile_of(const float* rp, int q) {
    const float rx = rp[q * 2 + 0] * (float)GW;
    const float ry = rp[q * 2 + 1] * (float)GH;
    const int tx = min(max((int)(rx * (1.0f / TS)), 0), TNX - 1);
    const int ty = min(max((int)(ry * (1.0f / TS)), 0), TNX - 1);
    return ty * TNX + tx;
}

__global__ void __launch_bounds__(256)
sort_zero(int* __restrict__ hist) {
    const int i = blockIdx.x * 256 + threadIdx.x;
    if (i < NT) hist[i] = 0;
}

__global__ void __launch_bounds__(256)
sort_hist(const float* __restrict__ rp, int* __restrict__ hist) {
    const int q = blockIdx.x * 256 + threadIdx.x;
    if (q >= NQ) return;
    atomicAdd(&hist[tile_of(rp, q)], 1);
}

__global__ void __launch_bounds__(64)
sort_scan(const int* __restrict__ hist, int* __restrict__ cursor) {
    const int lane = threadIdx.x;   // one wave
    int loc[10]; int t = 0;
#pragma unroll
    for (int j = 0; j < 10; ++j) {
        const int idx = lane * 10 + j;
        loc[j] = t;
        t += (idx < NT) ? hist[idx] : 0;
    }
    int s = t;
#pragma unroll
    for (int o = 1; o < 64; o <<= 1) {
        const int u = __shfl_up(s, o);
        if (lane >= o) s += u;
    }
    const int ex = s - t;
#pragma unroll
    for (int j = 0; j < 10; ++j) {
        const int idx = lane * 10 + j;
        if (idx < NT) cursor[idx] = ex + loc[j];
    }
}

__global__ void __launch_bounds__(256)
sort_scatter(const float* __restrict__ rp, int* __restrict__ cursor,
             int* __restrict__ perm) {
    const int q = blockIdx.x * 256 + threadIdx.x;
    if (q >= NQ) return;
    const int pos = atomicAdd(&cursor[tile_of(rp, q)], 1);
    perm[pos] = q;
}

// ---------------------------------------------------------------------------
// m97-style GEMM: C[M,N] = epi(A[M,256] @ Bt[N,256]^T + bias) — unchanged R2.
// EPI: 0 = fp32 out, 1 = exact-gelu -> bf16 out, 2 = bf16 out.
// ---------------------------------------------------------------------------
template <int EPI>
__global__ void __launch_bounds__(256)
gemm_bt(const unsigned short* __restrict__ A, const unsigned short* __restrict__ Bt,
        const float* __restrict__ bias, void* __restrict__ C,
        int M, int N, int ldc) {
    __shared__ __align__(16) unsigned short As[128 * 32];
    __shared__ __align__(16) unsigned short Bs[128 * 32];

    const int tid = threadIdx.x, lane = tid & 63, wave = tid >> 6;
    const int quad = lane >> 4, l16 = lane & 15;
    const int wm = wave >> 1, wn = wave & 1;
    const int bm0 = blockIdx.y * 128, bn0 = blockIdx.x * 128;

    f32x4 acc[4][4] = {};

    const int rl = lane >> 2;
    const int c8 = (lane & 3) * 8;

    for (int kt = 0; kt < 8; ++kt) {
        const int k0 = kt * 32;
        __syncthreads();
#pragma unroll
        for (int i = 0; i < 2; ++i) {
            const int rgrp = i * 64 + wave * 16;
            const int gA = min(bm0 + rgrp + rl, M - 1);
            const unsigned short* gpa = A + (size_t)gA * 256 + k0 + c8;
            __builtin_amdgcn_global_load_lds(
                (const __attribute__((address_space(1))) void*)gpa,
                (__attribute__((address_space(3))) void*)(As + (size_t)rgrp * 32),
                16, 0, 0);
            const int gB = min(bn0 + rgrp + rl, N - 1);
            const unsigned short* gpb = Bt + (size_t)gB * 256 + k0 + c8;
            __builtin_amdgcn_global_load_lds(
                (const __attribute__((address_space(1))) void*)gpb,
                (__attribute__((address_space(3))) void*)(Bs + (size_t)rgrp * 32),
                16, 0, 0);
        }
        __syncthreads();

        bf16x8 af[4], bw[4];
#pragma unroll
        for (int t = 0; t < 4; ++t) {
            af[t] = *(const bf16x8*)&As[(wm * 64 + t * 16 + l16) * 32 + quad * 8];
            bw[t] = *(const bf16x8*)&Bs[(wn * 64 + t * 16 + l16) * 32 + quad * 8];
        }
#pragma unroll
        for (int tm = 0; tm < 4; ++tm)
#pragma unroll
            for (int tn = 0; tn < 4; ++tn)
                acc[tm][tn] = __builtin_amdgcn_mfma_f32_16x16x32_bf16(
                    af[tm], bw[tn], acc[tm][tn], 0, 0, 0);
    }

#pragma unroll
    for (int tm = 0; tm < 4; ++tm) {
        const int row0 = bm0 + wm * 64 + tm * 16 + quad * 4;
#pragma unroll
        for (int tn = 0; tn < 4; ++tn) {
            const int col = bn0 + wn * 64 + tn * 16 + l16;
            if (col < N) {
                const float bv = bias[col];
#pragma unroll
                for (int r = 0; r < 4; ++r) {
                    const int row = row0 + r;
                    if (row < M) {
                        float x = acc[tm][tn][r] + bv;
                        if (EPI == 1) {
                            x = 0.5f * x * (1.0f + erff(x * 0.70710678118654752f));
                            ((unsigned short*)C)[(size_t)row * ldc + col] = f2bf(x);
                        } else if (EPI == 2) {
                            ((unsigned short*)C)[(size_t)row * ldc + col] = f2bf(x);
                        } else {
                            ((float*)C)[(size_t)row * ldc + col] = x;
                        }
                    }
                }
            }
        }
    }
}

// ---------------------------------------------------------------------------
// Deformable sampling over spatially-sorted queries.
// Block = 8 sorted queries x 8 heads x 4 slices. XCD swizzle keeps each
// XCD's share a contiguous spatial band (fits its 4 MB L2).
// ---------------------------------------------------------------------------
__global__ void __launch_bounds__(256)
msda_sample(const unsigned short* __restrict__ v,
            const unsigned short* __restrict__ oa,
            const float* __restrict__ rp,
            const int* __restrict__ perm,
            unsigned short* __restrict__ out) {
    const int b = blockIdx.x;
    const int w = (b & 7) * 625 + (b >> 3);   // XCD band swizzle (5000 blocks)
    const int tid = threadIdx.x;
    const int slot = tid >> 2;                // 0..63
    const int q = perm[w * 8 + (slot >> 3)];
    const int h = slot & 7;
    const int c0 = (tid & 3) * 8;

    const float rx = rp[q * 2 + 0] * (float)GW;
    const float ry = rp[q * 2 + 1] * (float)GH;

    const unsigned short* oaq = oa + (size_t)q * 144;
    float lg[NP];
    float mx = -1e30f;
#pragma unroll
    for (int p = 0; p < NP; ++p) {
        lg[p] = bf2f(oaq[96 + h * NP + p]);
        mx = fmaxf(mx, lg[p]);
    }
    float s = 0.0f;
#pragma unroll
    for (int p = 0; p < NP; ++p) { lg[p] = expf(lg[p] - mx); s += lg[p]; }
    const float inv = 1.0f / s;

    float acc[8] = {};
#pragma unroll
    for (int p = 0; p < NP; ++p) {
        const float aw = lg[p] * inv;
        const float lx = rx + bf2f(oaq[h * 12 + p * 2 + 0]) - 0.5f;
        const float ly = ry + bf2f(oaq[h * 12 + p * 2 + 1]) - 0.5f;
        const float fx0 = floorf(lx), fy0 = floorf(ly);
        const int x0 = (int)fx0, y0 = (int)fy0;
        const float fx = lx - fx0, fy = ly - fy0;
#pragma unroll
        for (int dy = 0; dy < 2; ++dy) {
            const int yi = y0 + dy;
            const float wyv = dy ? fy : 1.0f - fy;
#pragma unroll
            for (int dx = 0; dx < 2; ++dx) {
                const int xi = x0 + dx;
                const float wxv = dx ? fx : 1.0f - fx;
                const bool valid = (xi >= 0) & (xi < GW) & (yi >= 0) & (yi < GH);
                const int yc = min(max(yi, 0), GH - 1);
                const int xc = min(max(xi, 0), GW - 1);
                const float wgt = valid ? aw * wxv * wyv : 0.0f;
                const bf16x8 g = *(const bf16x8*)&v[((size_t)(yc * GW + xc)) * 256 + h * 32 + c0];
#pragma unroll
                for (int j = 0; j < 8; ++j)
                    acc[j] += bf2f((unsigned short)g[j]) * wgt;
            }
        }
    }
    bf16x8 o;
#pragma unroll
    for (int j = 0; j < 8; ++j) o[j] = (short)f2bf(acc[j]);
    *(bf16x8*)&out[(size_t)q * 256 + h * 32 + c0] = o;
}

// ---------------------------------------------------------------------------
// Fused residual + LayerNorm, D=256, one wave/row, 4 rows/block.
// RES_BF: residual is bf16. OUT_BF: emit bf16 (else fp32).
// ---------------------------------------------------------------------------
template <int RES_BF, int OUT_BF>
__global__ void __launch_bounds__(256)
ln_res(const float* __restrict__ x, const void* __restrict__ res,
       const float* __restrict__ g, const float* __restrict__ b,
       void* __restrict__ out, int M) {
    const int wave = threadIdx.x >> 6;
    const int lane = threadIdx.x & 63;
    const int row = blockIdx.x * 4 + wave;
    if (row >= M) return;

    const size_t base = (size_t)row * DIM + lane * 4;
    const float4 xv = *(const float4*)(x + base);
    float e[4];
    if (RES_BF) {
        const unsigned short* rb = (const unsigned short*)res + base;
        uint2 rv = *(const uint2*)rb;
        const unsigned short* rs = (const unsigned short*)&rv;
        e[0] = xv.x + bf2f(rs[0]); e[1] = xv.y + bf2f(rs[1]);
        e[2] = xv.z + bf2f(rs[2]); e[3] = xv.w + bf2f(rs[3]);
    } else {
        const float4 rv = *(const float4*)((const float*)res + base);
        e[0] = xv.x + rv.x; e[1] = xv.y + rv.y;
        e[2] = xv.z + rv.z; e[3] = xv.w + rv.w;
    }

    float s = e[0] + e[1] + e[2] + e[3];
    float sq = e[0] * e[0] + e[1] * e[1] + e[2] * e[2] + e[3] * e[3];
#pragma unroll
    for (int o = 1; o < 64; o <<= 1) {
        s += __shfl_xor(s, o);
        sq += __shfl_xor(sq, o);
    }
    const float mean = s * (1.0f / DIM);
    const float var = sq * (1.0f / DIM) - mean * mean;
    const float rstd = rsqrtf(var + 1e-5f);

    const float4 gv = *(const float4*)(g + lane * 4);
    const float4 bv = *(const float4*)(b + lane * 4);
    float o0 = (e[0] - mean) * rstd * gv.x + bv.x;
    float o1 = (e[1] - mean) * rstd * gv.y + bv.y;
    float o2 = (e[2] - mean) * rstd * gv.z + bv.z;
    float o3 = (e[3] - mean) * rstd * gv.w + bv.w;
    if (OUT_BF) {
        unsigned short ob[4] = {f2bf(o0), f2bf(o1), f2bf(o2), f2bf(o3)};
        *(uint2*)((unsigned short*)out + base) = *(uint2*)ob;
    } else {
        float4 o4 = {o0, o1, o2, o3};
        *(float4*)((float*)out + base) = o4;
    }
}

extern "C" void kernel_launch(void* const* d_in, const int* in_sizes, int n_in,
                              void* d_out, int out_size, void* d_ws, size_t ws_size,
                              hipStream_t stream) {
    const float* query  = (const float*)d_in[0];
    const float* value  = (const float*)d_in[1];
    const float* rp     = (const float*)d_in[2];
    const float* W_off  = (const float*)d_in[5];
    const float* b_off  = (const float*)d_in[6];
    const float* W_attn = (const float*)d_in[7];
    const float* b_attn = (const float*)d_in[8];
    const float* W_val  = (const float*)d_in[9];
    const float* b_val  = (const float*)d_in[10];
    const float* W_out  = (const float*)d_in[11];
    const float* b_out  = (const float*)d_in[12];
    const float* ln1_g  = (const float*)d_in[13];
    const float* ln1_b  = (const float*)d_in[14];
    const float* W1     = (const float*)d_in[15];
    const float* b1     = (const float*)d_in[16];
    const float* W2     = (const float*)d_in[17];
    const float* b2     = (const float*)d_in[18];
    const float* ln2_g  = (const float*)d_in[19];
    const float* ln2_b  = (const float*)d_in[20];

    char* ws = (char*)d_ws;
    // layout (bytes), max 73,730,048 <= 84,480,000:
    //  [0,        598016)   Bt weights (1168 x 256 bf16)
    //  [598016,   598592)   bias_oa (144 f32)
    //  [598592,   601600)   hist (625 i32, padded)
    //  [601600,   604608)   cursor (625 i32, padded)
    //  [604608,   764608)   perm (40000 i32)
    //  [770048,   21250048) query_bf -> h1_bf (after offattn GEMM)
    //  [21250048, 41730048) value_bf -> msda_bf (after Wval GEMM) -> y_bf (after Wout GEMM)
    //  [41730048, 62210048) v_bf (dead after sampling)
    //  [62210048, 73730048) oa_bf (dead after sampling)
    unsigned short* Bt       = (unsigned short*)ws;
    float*          bias_oa  = (float*)(ws + 598016);
    int*            hist     = (int*)(ws + 598592);
    int*            cursor   = (int*)(ws + 601600);
    int*            perm     = (int*)(ws + 604608);
    unsigned short* query_bf = (unsigned short*)(ws + 770048);
    unsigned short* h1_bf    = query_bf;
    unsigned short* value_bf = (unsigned short*)(ws + 21250048);
    unsigned short* msda_bf  = value_bf;
    unsigned short* y_bf     = value_bf;
    unsigned short* v_bf     = (unsigned short*)(ws + 41730048);
    unsigned short* oa_bf    = (unsigned short*)(ws + 62210048);
    float*          outp     = (float*)d_out;

    dim3 blk(256);
    f2b_kernel<<<dim3(10000), blk, 0, stream>>>(query, query_bf, value, value_bf);
    wtrans_kernel<<<dim3(4, 4, 6), blk, 0, stream>>>(W_val, W_off, W_attn, W_out, W1, W2,
                                                     b_off, b_attn, Bt, bias_oa);
    // spatial counting sort of queries
    sort_zero<<<dim3(3), blk, 0, stream>>>(hist);
    sort_hist<<<dim3(157), blk, 0, stream>>>(rp, hist);
    sort_scan<<<dim3(1), dim3(64), 0, stream>>>(hist, cursor);
    sort_scatter<<<dim3(157), blk, 0, stream>>>(rp, cursor, perm);
    // v = value @ W_val + b_val -> bf16
    gemm_bt<2><<<dim3(2, 313), blk, 0, stream>>>(value_bf, Bt, b_val, (void*)v_bf, NQ, 256, 256);
    // offattn = query @ [W_off|W_attn] + bias -> bf16 [NQ][144]
    gemm_bt<2><<<dim3(2, 313), blk, 0, stream>>>(query_bf, Bt + 256 * 256, bias_oa,
                                                 (void*)oa_bf, NQ, 144, 144);
    // sampling (sorted order) -> msda bf16
    msda_sample<<<dim3(5000), blk, 0, stream>>>(v_bf, oa_bf, rp, perm, msda_bf);
    // y_msda_pre = msda @ W_out + b_out (fp32, into d_out as scratch)
    gemm_bt<0><<<dim3(2, 313), blk, 0, stream>>>(msda_bf, Bt + 400 * 256, b_out,
                                                 (void*)outp, NQ, 256, 256);
    // y = LN(y_msda_pre + query) -> bf16 only
    ln_res<0, 1><<<dim3(10000), blk, 0, stream>>>(outp, query, ln1_g, ln1_b, (void*)y_bf, NQ);
    // h1 = gelu(y @ W1 + b1) -> bf16
    gemm_bt<1><<<dim3(2, 313), blk, 0, stream>>>(y_bf, Bt + 656 * 256, b1,
                                                 (void*)h1_bf, NQ, 256, 256);
    // y2p = h1 @ W2 + b2 (fp32, into d_out)
    gemm_bt<0><<<dim3(2, 313), blk, 0, stream>>>(h1_bf, Bt + 912 * 256, b2,
                                                 (void*)outp, NQ, 256, 256);
    // out = LN(y2p + y_bf), in place fp32
    ln_res<1, 0><<<dim3(10000), blk, 0, stream>>>(outp, y_bf, ln2_g, ln2_b, (void*)outp, NQ);
}

// Round 4
// 335.606 us; speedup vs baseline: 2.4602x; 1.0650x over previous
//
#include <hip/hip_runtime.h>
#include <math.h>

#define NQ 40000
#define DIM 256
#define NH 8
#define NP 6
#define HD 32
#define GH 200
#define GW 200
#define TS 8
#define TNX 25
#define NT 625

typedef short bf16x8 __attribute__((ext_vector_type(8)));
typedef float f32x4 __attribute__((ext_vector_type(4)));

__device__ __forceinline__ unsigned short f2bf(float f) {
    unsigned int u = __builtin_bit_cast(unsigned int, f);
    u += 0x7fffu + ((u >> 16) & 1u);
    return (unsigned short)(u >> 16);
}
__device__ __forceinline__ float bf2f(unsigned short h) {
    return __builtin_bit_cast(float, ((unsigned int)h) << 16);
}

// ---------------------------------------------------------------------------
// fp32 -> bf16 for query (blocks 0..4999) and value (5000..9999)
// ---------------------------------------------------------------------------
__global__ void __launch_bounds__(256)
f2b_kernel(const float* __restrict__ q, unsigned short* __restrict__ qd,
           const float* __restrict__ v, unsigned short* __restrict__ vd) {
    int b = blockIdx.x;
    const float* src; unsigned short* dst;
    if (b < 5000) { src = q; dst = qd; } else { src = v; dst = vd; b -= 5000; }
    const int i = b * 256 + threadIdx.x;
    const float4* s = (const float4*)src;
    float4 a = s[(size_t)i * 2], c = s[(size_t)i * 2 + 1];
    bf16x8 o;
    o[0] = (short)f2bf(a.x); o[1] = (short)f2bf(a.y);
    o[2] = (short)f2bf(a.z); o[3] = (short)f2bf(a.w);
    o[4] = (short)f2bf(c.x); o[5] = (short)f2bf(c.y);
    o[6] = (short)f2bf(c.z); o[7] = (short)f2bf(c.w);
    *(bf16x8*)(dst + (size_t)i * 8) = o;
}

// ---------------------------------------------------------------------------
// Weight prep: transpose K x N fp32 -> [N][K] bf16 rows into Bt.
// Row offsets: Wval 0, Woff 256, Wattn 352, Wout 400, W1 656, W2 912.
// ---------------------------------------------------------------------------
__global__ void __launch_bounds__(256)
wtrans_kernel(const float* __restrict__ Wval, const float* __restrict__ Woff,
              const float* __restrict__ Wattn, const float* __restrict__ Wout,
              const float* __restrict__ W1, const float* __restrict__ W2,
              const float* __restrict__ b_off, const float* __restrict__ b_attn,
              unsigned short* __restrict__ Bt, float* __restrict__ bias_oa) {
    __shared__ float T[64][65];
    const int m = blockIdx.z;
    const float* src; int N; int dr0;
    if (m == 0)      { src = Wval;  N = 256; dr0 = 0; }
    else if (m == 1) { src = Woff;  N = 96;  dr0 = 256; }
    else if (m == 2) { src = Wattn; N = 48;  dr0 = 352; }
    else if (m == 3) { src = Wout;  N = 256; dr0 = 400; }
    else if (m == 4) { src = W1;    N = 256; dr0 = 656; }
    else             { src = W2;    N = 256; dr0 = 912; }

    if (m == 1 && blockIdx.x == 0 && blockIdx.y == 0 && threadIdx.x < 144)
        bias_oa[threadIdx.x] = threadIdx.x < 96 ? b_off[threadIdx.x]
                                                : b_attn[threadIdx.x - 96];

    const int n0 = blockIdx.x * 64, k0 = blockIdx.y * 64;
    if (n0 >= N) return;
    const int col = threadIdx.x & 63, rg = threadIdx.x >> 6;
#pragma unroll
    for (int i = 0; i < 16; ++i) {
        const int r = rg + 4 * i;
        T[r][col] = (n0 + col < N) ? src[(size_t)(k0 + r) * N + n0 + col] : 0.0f;
    }
    __syncthreads();
#pragma unroll
    for (int i = 0; i < 16; ++i) {
        const int nl = rg + 4 * i;
        if (n0 + nl < N)
            Bt[(size_t)(dr0 + n0 + nl) * 256 + k0 + col] = f2bf(T[col][nl]);
    }
}

// ---------------------------------------------------------------------------
// Query spatial counting sort by 8x8-cell tile.
// ---------------------------------------------------------------------------
__device__ __forceinline__ int tile_of(const float* rp, int q) {
    const float rx = rp[q * 2 + 0] * (float)GW;
    const float ry = rp[q * 2 + 1] * (float)GH;
    const int tx = min(max((int)(rx * (1.0f / TS)), 0), TNX - 1);
    const int ty = min(max((int)(ry * (1.0f / TS)), 0), TNX - 1);
    return ty * TNX + tx;
}

__global__ void __launch_bounds__(256)
sort_zero(int* __restrict__ hist) {
    const int i = blockIdx.x * 256 + threadIdx.x;
    if (i < NT) hist[i] = 0;
}

__global__ void __launch_bounds__(256)
sort_hist(const float* __restrict__ rp, int* __restrict__ hist) {
    const int q = blockIdx.x * 256 + threadIdx.x;
    if (q >= NQ) return;
    atomicAdd(&hist[tile_of(rp, q)], 1);
}

__global__ void __launch_bounds__(64)
sort_scan(const int* __restrict__ hist, int* __restrict__ cursor) {
    const int lane = threadIdx.x;
    int loc[10]; int t = 0;
#pragma unroll
    for (int j = 0; j < 10; ++j) {
        const int idx = lane * 10 + j;
        loc[j] = t;
        t += (idx < NT) ? hist[idx] : 0;
    }
    int s = t;
#pragma unroll
    for (int o = 1; o < 64; o <<= 1) {
        const int u = __shfl_up(s, o);
        if (lane >= o) s += u;
    }
    const int ex = s - t;
#pragma unroll
    for (int j = 0; j < 10; ++j) {
        const int idx = lane * 10 + j;
        if (idx < NT) cursor[idx] = ex + loc[j];
    }
}

__global__ void __launch_bounds__(256)
sort_scatter(const float* __restrict__ rp, int* __restrict__ cursor,
             int* __restrict__ perm) {
    const int q = blockIdx.x * 256 + threadIdx.x;
    if (q >= NQ) return;
    const int pos = atomicAdd(&cursor[tile_of(rp, q)], 1);
    perm[pos] = q;
}

// ---------------------------------------------------------------------------
// gemm64: C[M,256] = epi(A[M,256] @ Bt[256,256]^T + bias)
// BM=64, BN=256 (full row per block), BK=32, 4 waves (each 64x64),
// explicit LDS double-buffer via global_load_lds width-16.
// EPI: 1 = exact-gelu -> bf16, 2 = bf16,
//      3 = LN(x + res_fp32) -> bf16, 4 = LN(x + res_bf16) -> fp32.
// M must be a multiple of 64.
// ---------------------------------------------------------------------------
template <int EPI>
__global__ void __launch_bounds__(256)
gemm64(const unsigned short* __restrict__ A, const unsigned short* __restrict__ Bt,
       const float* __restrict__ bias, const void* __restrict__ res,
       const float* __restrict__ lng, const float* __restrict__ lnb,
       void* __restrict__ C, int M) {
    __shared__ __align__(16) unsigned short As[2][64 * 32];
    __shared__ __align__(16) unsigned short Bs[2][256 * 32];
    __shared__ __align__(16) float red[64][4][2];

    const int tid = threadIdx.x, lane = tid & 63, wave = tid >> 6;
    const int quad = lane >> 4, l16 = lane & 15;
    const int bm0 = blockIdx.x * 64;
    const int r16 = lane >> 2;          // 0..15 (row within 16-row group)
    const int ch = (lane & 3) * 8;      // k-element offset 0,8,16,24

    f32x4 acc[4][4] = {};

    // --- staging: one A inst + four B insts per wave per K-step ---
    auto stage = [&](int kt, int buf) {
        const int k0 = kt * 32;
        {
            const int row = wave * 16 + r16;
            const unsigned short* gp = A + (size_t)(bm0 + row) * 256 + k0 + ch;
            __builtin_amdgcn_global_load_lds(
                (const __attribute__((address_space(1))) void*)gp,
                (__attribute__((address_space(3))) void*)(&As[buf][wave * 16 * 32]),
                16, 0, 0);
        }
#pragma unroll
        for (int j = 0; j < 4; ++j) {
            const int rowbase = (wave * 4 + j) * 16;
            const unsigned short* gp = Bt + (size_t)(rowbase + r16) * 256 + k0 + ch;
            __builtin_amdgcn_global_load_lds(
                (const __attribute__((address_space(1))) void*)gp,
                (__attribute__((address_space(3))) void*)(&Bs[buf][rowbase * 32]),
                16, 0, 0);
        }
    };

    stage(0, 0);
    __syncthreads();

    for (int kt = 0; kt < 8; ++kt) {
        const int cur = kt & 1;
        if (kt < 7) stage(kt + 1, 1 - cur);

        bf16x8 af[4], bw[4];
#pragma unroll
        for (int t = 0; t < 4; ++t) {
            af[t] = *(const bf16x8*)&As[cur][(t * 16 + l16) * 32 + quad * 8];
            bw[t] = *(const bf16x8*)&Bs[cur][(wave * 64 + t * 16 + l16) * 32 + quad * 8];
        }
#pragma unroll
        for (int tm = 0; tm < 4; ++tm)
#pragma unroll
            for (int tn = 0; tn < 4; ++tn)
                acc[tm][tn] = __builtin_amdgcn_mfma_f32_16x16x32_bf16(
                    af[tm], bw[tn], acc[tm][tn], 0, 0, 0);
        __syncthreads();
    }

    // --- epilogue. C/D layout: col = lane&15, row = quad*4 + reg ---
    float bias4[4];
#pragma unroll
    for (int tn = 0; tn < 4; ++tn) bias4[tn] = bias[wave * 64 + tn * 16 + l16];

    if (EPI == 1 || EPI == 2) {
#pragma unroll
        for (int tm = 0; tm < 4; ++tm) {
            const int row0 = bm0 + tm * 16 + quad * 4;
#pragma unroll
            for (int tn = 0; tn < 4; ++tn) {
                const int col = wave * 64 + tn * 16 + l16;
#pragma unroll
                for (int r = 0; r < 4; ++r) {
                    float x = acc[tm][tn][r] + bias4[tn];
                    if (EPI == 1) x = 0.5f * x * (1.0f + erff(x * 0.70710678118654752f));
                    ((unsigned short*)C)[(size_t)(row0 + r) * 256 + col] = f2bf(x);
                }
            }
        }
        return;
    }

    // LN variants: add bias + residual, then row stats over all 256 cols.
#pragma unroll
    for (int tm = 0; tm < 4; ++tm) {
#pragma unroll
        for (int r = 0; r < 4; ++r) {
            const size_t rb = (size_t)(bm0 + tm * 16 + quad * 4 + r) * 256;
#pragma unroll
            for (int tn = 0; tn < 4; ++tn) {
                const int col = wave * 64 + tn * 16 + l16;
                float e = acc[tm][tn][r] + bias4[tn];
                if (EPI == 3) e += ((const float*)res)[rb + col];
                else          e += bf2f(((const unsigned short*)res)[rb + col]);
                acc[tm][tn][r] = e;
            }
        }
    }
    // per-wave partial (sum, sumsq) per row over this wave's 64 cols
#pragma unroll
    for (int tm = 0; tm < 4; ++tm) {
#pragma unroll
        for (int r = 0; r < 4; ++r) {
            float s = 0.0f, sq = 0.0f;
#pragma unroll
            for (int tn = 0; tn < 4; ++tn) {
                const float e = acc[tm][tn][r];
                s += e; sq += e * e;
            }
#pragma unroll
            for (int o = 1; o < 16; o <<= 1) {
                s += __shfl_xor(s, o);
                sq += __shfl_xor(sq, o);
            }
            if (l16 == 0) {
                const int row = tm * 16 + quad * 4 + r;
                red[row][wave][0] = s;
                red[row][wave][1] = sq;
            }
        }
    }
    __syncthreads();

    float gv[4], bvv[4];
#pragma unroll
    for (int tn = 0; tn < 4; ++tn) {
        const int col = wave * 64 + tn * 16 + l16;
        gv[tn] = lng[col];
        bvv[tn] = lnb[col];
    }
#pragma unroll
    for (int tm = 0; tm < 4; ++tm) {
#pragma unroll
        for (int r = 0; r < 4; ++r) {
            const int row = tm * 16 + quad * 4 + r;
            const float4 p0 = *(const float4*)&red[row][0][0];
            const float4 p1 = *(const float4*)&red[row][2][0];
            const float sum = p0.x + p0.z + p1.x + p1.z;
            const float sumsq = p0.y + p0.w + p1.y + p1.w;
            const float mean = sum * (1.0f / 256.0f);
            const float var = sumsq * (1.0f / 256.0f) - mean * mean;
            const float rstd = rsqrtf(var + 1e-5f);
            const size_t rb = (size_t)(bm0 + row) * 256;
#pragma unroll
            for (int tn = 0; tn < 4; ++tn) {
                const int col = wave * 64 + tn * 16 + l16;
                const float o = (acc[tm][tn][r] - mean) * rstd * gv[tn] + bvv[tn];
                if (EPI == 3) ((unsigned short*)C)[rb + col] = f2bf(o);
                else          ((float*)C)[rb + col] = o;
            }
        }
    }
}

// ---------------------------------------------------------------------------
// Old m97-style GEMM kept only for the N=144 offattn projection.
// ---------------------------------------------------------------------------
__global__ void __launch_bounds__(256)
gemm_bt(const unsigned short* __restrict__ A, const unsigned short* __restrict__ Bt,
        const float* __restrict__ bias, unsigned short* __restrict__ C,
        int M, int N, int ldc) {
    __shared__ __align__(16) unsigned short As[128 * 32];
    __shared__ __align__(16) unsigned short Bs[128 * 32];

    const int tid = threadIdx.x, lane = tid & 63, wave = tid >> 6;
    const int quad = lane >> 4, l16 = lane & 15;
    const int wm = wave >> 1, wn = wave & 1;
    const int bm0 = blockIdx.y * 128, bn0 = blockIdx.x * 128;

    f32x4 acc[4][4] = {};
    const int rl = lane >> 2;
    const int c8 = (lane & 3) * 8;

    for (int kt = 0; kt < 8; ++kt) {
        const int k0 = kt * 32;
        __syncthreads();
#pragma unroll
        for (int i = 0; i < 2; ++i) {
            const int rgrp = i * 64 + wave * 16;
            const int gA = min(bm0 + rgrp + rl, M - 1);
            const unsigned short* gpa = A + (size_t)gA * 256 + k0 + c8;
            __builtin_amdgcn_global_load_lds(
                (const __attribute__((address_space(1))) void*)gpa,
                (__attribute__((address_space(3))) void*)(As + (size_t)rgrp * 32),
                16, 0, 0);
            const int gB = min(bn0 + rgrp + rl, N - 1);
            const unsigned short* gpb = Bt + (size_t)gB * 256 + k0 + c8;
            __builtin_amdgcn_global_load_lds(
                (const __attribute__((address_space(1))) void*)gpb,
                (__attribute__((address_space(3))) void*)(Bs + (size_t)rgrp * 32),
                16, 0, 0);
        }
        __syncthreads();

        bf16x8 af[4], bw[4];
#pragma unroll
        for (int t = 0; t < 4; ++t) {
            af[t] = *(const bf16x8*)&As[(wm * 64 + t * 16 + l16) * 32 + quad * 8];
            bw[t] = *(const bf16x8*)&Bs[(wn * 64 + t * 16 + l16) * 32 + quad * 8];
        }
#pragma unroll
        for (int tm = 0; tm < 4; ++tm)
#pragma unroll
            for (int tn = 0; tn < 4; ++tn)
                acc[tm][tn] = __builtin_amdgcn_mfma_f32_16x16x32_bf16(
                    af[tm], bw[tn], acc[tm][tn], 0, 0, 0);
    }

#pragma unroll
    for (int tm = 0; tm < 4; ++tm) {
        const int row0 = bm0 + wm * 64 + tm * 16 + quad * 4;
#pragma unroll
        for (int tn = 0; tn < 4; ++tn) {
            const int col = bn0 + wn * 64 + tn * 16 + l16;
            if (col < N) {
                const float bv = bias[col];
#pragma unroll
                for (int r = 0; r < 4; ++r) {
                    const int row = row0 + r;
                    if (row < M)
                        C[(size_t)row * ldc + col] = f2bf(acc[tm][tn][r] + bv);
                }
            }
        }
    }
}

// ---------------------------------------------------------------------------
// Deformable sampling over spatially-sorted queries (unchanged from R3).
// ---------------------------------------------------------------------------
__global__ void __launch_bounds__(256)
msda_sample(const unsigned short* __restrict__ v,
            const unsigned short* __restrict__ oa,
            const float* __restrict__ rp,
            const int* __restrict__ perm,
            unsigned short* __restrict__ out) {
    const int b = blockIdx.x;
    const int w = (b & 7) * 625 + (b >> 3);
    const int tid = threadIdx.x;
    const int slot = tid >> 2;
    const int q = perm[w * 8 + (slot >> 3)];
    const int h = slot & 7;
    const int c0 = (tid & 3) * 8;

    const float rx = rp[q * 2 + 0] * (float)GW;
    const float ry = rp[q * 2 + 1] * (float)GH;

    const unsigned short* oaq = oa + (size_t)q * 144;
    float lg[NP];
    float mx = -1e30f;
#pragma unroll
    for (int p = 0; p < NP; ++p) {
        lg[p] = bf2f(oaq[96 + h * NP + p]);
        mx = fmaxf(mx, lg[p]);
    }
    float s = 0.0f;
#pragma unroll
    for (int p = 0; p < NP; ++p) { lg[p] = expf(lg[p] - mx); s += lg[p]; }
    const float inv = 1.0f / s;

    float acc[8] = {};
#pragma unroll
    for (int p = 0; p < NP; ++p) {
        const float aw = lg[p] * inv;
        const float lx = rx + bf2f(oaq[h * 12 + p * 2 + 0]) - 0.5f;
        const float ly = ry + bf2f(oaq[h * 12 + p * 2 + 1]) - 0.5f;
        const float fx0 = floorf(lx), fy0 = floorf(ly);
        const int x0 = (int)fx0, y0 = (int)fy0;
        const float fx = lx - fx0, fy = ly - fy0;
#pragma unroll
        for (int dy = 0; dy < 2; ++dy) {
            const int yi = y0 + dy;
            const float wyv = dy ? fy : 1.0f - fy;
#pragma unroll
            for (int dx = 0; dx < 2; ++dx) {
                const int xi = x0 + dx;
                const float wxv = dx ? fx : 1.0f - fx;
                const bool valid = (xi >= 0) & (xi < GW) & (yi >= 0) & (yi < GH);
                const int yc = min(max(yi, 0), GH - 1);
                const int xc = min(max(xi, 0), GW - 1);
                const float wgt = valid ? aw * wxv * wyv : 0.0f;
                const bf16x8 g = *(const bf16x8*)&v[((size_t)(yc * GW + xc)) * 256 + h * 32 + c0];
#pragma unroll
                for (int j = 0; j < 8; ++j)
                    acc[j] += bf2f((unsigned short)g[j]) * wgt;
            }
        }
    }
    bf16x8 o;
#pragma unroll
    for (int j = 0; j < 8; ++j) o[j] = (short)f2bf(acc[j]);
    *(bf16x8*)&out[(size_t)q * 256 + h * 32 + c0] = o;
}

extern "C" void kernel_launch(void* const* d_in, const int* in_sizes, int n_in,
                              void* d_out, int out_size, void* d_ws, size_t ws_size,
                              hipStream_t stream) {
    const float* query  = (const float*)d_in[0];
    const float* value  = (const float*)d_in[1];
    const float* rp     = (const float*)d_in[2];
    const float* W_off  = (const float*)d_in[5];
    const float* b_off  = (const float*)d_in[6];
    const float* W_attn = (const float*)d_in[7];
    const float* b_attn = (const float*)d_in[8];
    const float* W_val  = (const float*)d_in[9];
    const float* b_val  = (const float*)d_in[10];
    const float* W_out  = (const float*)d_in[11];
    const float* b_out  = (const float*)d_in[12];
    const float* ln1_g  = (const float*)d_in[13];
    const float* ln1_b  = (const float*)d_in[14];
    const float* W1     = (const float*)d_in[15];
    const float* b1     = (const float*)d_in[16];
    const float* W2     = (const float*)d_in[17];
    const float* b2     = (const float*)d_in[18];
    const float* ln2_g  = (const float*)d_in[19];
    const float* ln2_b  = (const float*)d_in[20];

    char* ws = (char*)d_ws;
    // layout (bytes), max 73,730,048:
    //  [0,        598016)   Bt (1168 x 256 bf16)
    //  [598016,   598592)   bias_oa
    //  [598592,   601600)   hist
    //  [601600,   604608)   cursor
    //  [604608,   764608)   perm
    //  [770048,   21250048) query_bf -> h1_bf (after offattn GEMM + W1 GEMM src dead)
    //  [21250048, 41730048) value_bf -> msda_bf (after Wval GEMM)
    //  [41730048, 62210048) v_bf -> y_bf (after sampling)
    //  [62210048, 73730048) oa_bf (dead after sampling)
    unsigned short* Bt       = (unsigned short*)ws;
    float*          bias_oa  = (float*)(ws + 598016);
    int*            hist     = (int*)(ws + 598592);
    int*            cursor   = (int*)(ws + 601600);
    int*            perm     = (int*)(ws + 604608);
    unsigned short* query_bf = (unsigned short*)(ws + 770048);
    unsigned short* h1_bf    = query_bf;
    unsigned short* value_bf = (unsigned short*)(ws + 21250048);
    unsigned short* msda_bf  = value_bf;
    unsigned short* v_bf     = (unsigned short*)(ws + 41730048);
    unsigned short* y_bf     = v_bf;
    unsigned short* oa_bf    = (unsigned short*)(ws + 62210048);
    float*          outp     = (float*)d_out;

    dim3 blk(256);
    f2b_kernel<<<dim3(10000), blk, 0, stream>>>(query, query_bf, value, value_bf);
    wtrans_kernel<<<dim3(4, 4, 6), blk, 0, stream>>>(W_val, W_off, W_attn, W_out, W1, W2,
                                                     b_off, b_attn, Bt, bias_oa);
    sort_zero<<<dim3(3), blk, 0, stream>>>(hist);
    sort_hist<<<dim3(157), blk, 0, stream>>>(rp, hist);
    sort_scan<<<dim3(1), dim3(64), 0, stream>>>(hist, cursor);
    sort_scatter<<<dim3(157), blk, 0, stream>>>(rp, cursor, perm);
    // v = value @ W_val + b_val -> bf16
    gemm64<2><<<dim3(625), blk, 0, stream>>>(value_bf, Bt, b_val, nullptr, nullptr, nullptr,
                                             (void*)v_bf, NQ);
    // offattn = query @ [W_off|W_attn] + bias -> bf16 [NQ][144]
    gemm_bt<<<dim3(2, 313), blk, 0, stream>>>(query_bf, Bt + 256 * 256, bias_oa,
                                              oa_bf, NQ, 144, 144);
    // sampling (sorted order) -> msda bf16
    msda_sample<<<dim3(5000), blk, 0, stream>>>(v_bf, oa_bf, rp, perm, msda_bf);
    // y = LN(msda @ W_out + b_out + query) -> bf16   (v_bf region now free)
    gemm64<3><<<dim3(625), blk, 0, stream>>>(msda_bf, Bt + 400 * 256, b_out,
                                             (const void*)query, ln1_g, ln1_b,
                                             (void*)y_bf, NQ);
    // h1 = gelu(y @ W1 + b1) -> bf16
    gemm64<1><<<dim3(625), blk, 0, stream>>>(y_bf, Bt + 656 * 256, b1, nullptr, nullptr,
                                             nullptr, (void*)h1_bf, NQ);
    // out = LN(h1 @ W2 + b2 + y) -> fp32
    gemm64<4><<<dim3(625), blk, 0, stream>>>(h1_bf, Bt + 912 * 256, b2,
                                             (const void*)y_bf, ln2_g, ln2_b,
                                             (void*)outp, NQ);
}